// Round 1
// baseline (36041.815 us; speedup 1.0000x reference)
//
#include <hip/hip_runtime.h>

// Problem constants
#define TT   1024      // timesteps
#define BB   64        // batch
#define FF   256       // input features
#define HH   2048      // LSTM units
#define G4   8192      // 4*H
#define KTOT 2304      // F + H
#define KP   2312      // padded LDS K-stride (elements): 2312*2B = 4624B, 16B-aligned, 2-way bank alias (free)
#define NBLK 256
#define NTHR 256
#define SMEM_BYTES (32 * KP * 2 + 64 * 33 * 4)   // W slice (144.5KB) + z tile (8.25KB) = 156,416 B

typedef __attribute__((ext_vector_type(8))) short bf16x8;
typedef __attribute__((ext_vector_type(4))) float f32x4;

__device__ __forceinline__ unsigned short f2bf(float f) {
  unsigned u = __float_as_uint(f);
  u += 0x7FFFu + ((u >> 16) & 1u);        // round-to-nearest-even
  return (unsigned short)(u >> 16);
}
__device__ __forceinline__ float sigm(float x) { return 1.0f / (1.0f + __expf(-x)); }
__device__ __forceinline__ float tanhfast(float x) {
  x = fminf(fmaxf(x, -15.0f), 15.0f);     // clamp: avoid inf/inf -> NaN
  float e = __expf(2.0f * x);
  return (e - 1.0f) / (e + 1.0f);
}

// Persistent LSTM kernel: 256 blocks (1 per CU), block j owns h-columns [8j, 8j+8).
// Weights for its 32 z-columns live in LDS (bf16, column-major, padded stride KP).
// h double-buffered in global (bf16); c in registers; one grid barrier per step.
__global__ void __launch_bounds__(NTHR, 1) lstm_persist(
    const float* __restrict__ x,          // [B][T][F] fp32
    const float* __restrict__ Wk,         // [F][4H]
    const float* __restrict__ Wr,         // [H][4H]
    const float* __restrict__ bias,       // [4H]
    unsigned short* __restrict__ hbuf0,   // [B][H] bf16
    unsigned short* __restrict__ hbuf1,   // [B][H] bf16
    float* __restrict__ hTf,              // [B][H] fp32 (final h)
    unsigned* __restrict__ cnt)           // barrier counter (monotonic)
{
  extern __shared__ char smem[];
  unsigned short* Wl = (unsigned short*)smem;        // [32][KP]
  float* zl = (float*)(smem + 32 * KP * 2);          // [64][33] padded

  const int tid = threadIdx.x;
  const int j = blockIdx.x;

  // ---- stage weight slice into LDS as bf16 (one-time) ----
  // LDS col cc in [0,32): gate = cc>>3, h-col = j*8 + (cc&7); global z-col = gate*H + j*8 + (cc&7)
  for (int idx = tid; idx < 32 * KTOT; idx += NTHR) {
    int cc = idx & 31;
    int k  = idx >> 5;
    int zc = (cc >> 3) * HH + j * 8 + (cc & 7);
    float wv = (k < FF) ? Wk[(size_t)k * G4 + zc] : Wr[(size_t)(k - FF) * G4 + zc];
    Wl[cc * KP + k] = f2bf(wv);
  }
  __syncthreads();

  // MFMA geometry: wave wid owns M-tile (16 batch rows), both N-tiles (32 cols)
  const int lane = tid & 63;
  const int wid  = tid >> 6;               // 0..3
  const int row  = wid * 16 + (lane & 15); // batch row for A fragment
  const int ko   = (lane >> 4) * 8;        // k offset within K-step of 32
  const int cl   = lane & 15;              // C/D column within tile
  const int rg   = lane >> 4;              // C/D row group

  // gate-phase constants: thread handles (b, col) for b = tid>>3 and b+32, col = j*8 + (tid&7)
  const int hc  = tid & 7;
  const int bb0 = tid >> 3;                // 0..31
  const int col = j * 8 + hc;
  const float bi  = bias[col];
  const float bf_ = bias[HH + col];
  const float bg  = bias[2 * HH + col];
  const float bo_ = bias[3 * HH + col];
  float c0 = 0.0f, c1 = 0.0f;

  const unsigned short* Wl_b0 = Wl + (0  + cl) * KP;
  const unsigned short* Wl_b1 = Wl + (16 + cl) * KP;

  for (int t = 0; t < TT; ++t) {
    const unsigned short* hr = (t & 1) ? hbuf1 : hbuf0;
    unsigned short*       hw = (t & 1) ? hbuf0 : hbuf1;

    f32x4 acc0 = {0.f, 0.f, 0.f, 0.f};
    f32x4 acc1 = {0.f, 0.f, 0.f, 0.f};

    // ---- x part: k in [0, 256), fp32 -> bf16 on the fly ----
    const float* xr = x + ((size_t)row * TT + t) * FF;
    #pragma unroll
    for (int kk = 0; kk < FF; kk += 32) {
      const float4 v0 = *(const float4*)(xr + kk + ko);
      const float4 v1 = *(const float4*)(xr + kk + ko + 4);
      bf16x8 a;
      a[0] = (short)f2bf(v0.x); a[1] = (short)f2bf(v0.y);
      a[2] = (short)f2bf(v0.z); a[3] = (short)f2bf(v0.w);
      a[4] = (short)f2bf(v1.x); a[5] = (short)f2bf(v1.y);
      a[6] = (short)f2bf(v1.z); a[7] = (short)f2bf(v1.w);
      bf16x8 b0 = *(const bf16x8*)(Wl_b0 + kk + ko);
      bf16x8 b1 = *(const bf16x8*)(Wl_b1 + kk + ko);
      acc0 = __builtin_amdgcn_mfma_f32_16x16x32_bf16(a, b0, acc0, 0, 0, 0);
      acc1 = __builtin_amdgcn_mfma_f32_16x16x32_bf16(a, b1, acc1, 0, 0, 0);
    }

    // ---- h part: k in [256, 2304), bf16 direct ----
    const unsigned short* hrow = hr + row * HH;
    #pragma unroll 8
    for (int kk = 0; kk < HH; kk += 32) {
      bf16x8 a  = *(const bf16x8*)(hrow + kk + ko);
      bf16x8 b0 = *(const bf16x8*)(Wl_b0 + FF + kk + ko);
      bf16x8 b1 = *(const bf16x8*)(Wl_b1 + FF + kk + ko);
      acc0 = __builtin_amdgcn_mfma_f32_16x16x32_bf16(a, b0, acc0, 0, 0, 0);
      acc1 = __builtin_amdgcn_mfma_f32_16x16x32_bf16(a, b1, acc1, 0, 0, 0);
    }

    // ---- scatter z to LDS (C/D layout: col = lane&15, row = (lane>>4)*4 + reg) ----
    #pragma unroll
    for (int r = 0; r < 4; ++r) {
      int b = wid * 16 + rg * 4 + r;
      zl[b * 33 + cl]      = acc0[r];
      zl[b * 33 + 16 + cl] = acc1[r];
    }
    __syncthreads();

    // ---- gates: i,f,g,o ; c = f*c + i*g ; h = o*tanh(c) ----
    #pragma unroll
    for (int p = 0; p < 2; ++p) {
      int b = bb0 + p * 32;
      float zi = zl[b * 33 + hc]      + bi;
      float zf = zl[b * 33 + 8 + hc]  + bf_;
      float zg = zl[b * 33 + 16 + hc] + bg;
      float zo = zl[b * 33 + 24 + hc] + bo_;
      float ig = sigm(zi), fg = sigm(zf), gg = tanhfast(zg), og = sigm(zo);
      float& c = p ? c1 : c0;
      c = fg * c + ig * gg;
      float h = og * tanhfast(c);
      hw[b * HH + col] = f2bf(h);
      if (t == TT - 1) hTf[b * HH + col] = h;
    }

    // ---- grid barrier (monotonic counter; skip after last step) ----
    if (t < TT - 1) {
      __syncthreads();                      // drains all waves' h stores (vmcnt(0) before s_barrier)
      if (tid == 0) {
        __threadfence();                    // agent-scope release: flush this XCD's L2
        __hip_atomic_fetch_add(cnt, 1u, __ATOMIC_RELEASE, __HIP_MEMORY_SCOPE_AGENT);
        const unsigned target = (unsigned)(t + 1) * NBLK;
        while (__hip_atomic_load(cnt, __ATOMIC_ACQUIRE, __HIP_MEMORY_SCOPE_AGENT) < target) {
          __builtin_amdgcn_s_sleep(4);
        }
        __threadfence();                    // acquire: invalidate stale L1/L2 lines
      }
      __syncthreads();
    }
  }
}

// Epilogue: y1 = relu(hT @ Wd + bd)  [64,512]
__global__ void dense1(const float* __restrict__ hT, const float* __restrict__ Wd,
                       const float* __restrict__ bd, float* __restrict__ y1) {
  int o = blockIdx.x * blockDim.x + threadIdx.x;   // 0..32767
  int b = o >> 9, n = o & 511;
  float acc = bd[n];
  const float* hrow = hT + b * HH;
  const float* wcol = Wd + n;
  #pragma unroll 8
  for (int k = 0; k < HH; ++k) acc = fmaf(hrow[k], wcol[(size_t)k * 512], acc);
  y1[o] = fmaxf(acc, 0.0f);
}

// y = relu(y1 @ Wo + bo)  [64,1]
__global__ void dense2(const float* __restrict__ y1, const float* __restrict__ Wo,
                       const float* __restrict__ bo, float* __restrict__ out) {
  int b = threadIdx.x;                              // 64 threads
  float acc = bo[0];
  const float* rowp = y1 + b * 512;
  for (int n = 0; n < 512; ++n) acc = fmaf(rowp[n], Wo[n], acc);
  out[b] = fmaxf(acc, 0.0f);
}

extern "C" void kernel_launch(void* const* d_in, const int* in_sizes, int n_in,
                              void* d_out, int out_size, void* d_ws, size_t ws_size,
                              hipStream_t stream) {
  const float* x    = (const float*)d_in[0];
  const float* Wk   = (const float*)d_in[1];
  const float* Wr   = (const float*)d_in[2];
  const float* bias = (const float*)d_in[3];
  const float* Wd   = (const float*)d_in[4];
  const float* bd   = (const float*)d_in[5];
  const float* Wo   = (const float*)d_in[6];
  const float* bo   = (const float*)d_in[7];
  float* out = (float*)d_out;

  // workspace layout (~1.2 MB)
  char* w = (char*)d_ws;
  unsigned short* hbuf0 = (unsigned short*)(w);                // 262144 B
  unsigned short* hbuf1 = (unsigned short*)(w + 262144);       // 262144 B
  float* hTf            = (float*)(w + 524288);                // 524288 B
  float* y1             = (float*)(w + 1048576);               // 131072 B
  unsigned* cnt         = (unsigned*)(w + 1179648);            // 64 B

  // deterministic per-call init (graph-replay safe)
  hipMemsetAsync(hbuf0, 0, (size_t)BB * HH * 2, stream);
  hipMemsetAsync(cnt, 0, 64, stream);

  // allow >64KB dynamic LDS (gfx950 has 160KB/CU)
  hipFuncSetAttribute((const void*)lstm_persist,
                      hipFuncAttributeMaxDynamicSharedMemorySize, SMEM_BYTES);

  void* args[] = { (void*)&x, (void*)&Wk, (void*)&Wr, (void*)&bias,
                   (void*)&hbuf0, (void*)&hbuf1, (void*)&hTf, (void*)&cnt };
  hipLaunchCooperativeKernel((const void*)lstm_persist, dim3(NBLK), dim3(NTHR),
                             args, SMEM_BYTES, stream);

  dense1<<<dim3(128), dim3(256), 0, stream>>>(hTf, Wd, bd, y1);
  dense2<<<dim3(1), dim3(64), 0, stream>>>(y1, Wo, bo, out);
}

// Round 2
// 16306.650 us; speedup vs baseline: 2.2103x; 2.2103x over previous
//
#include <hip/hip_runtime.h>

// Problem constants
#define TT   1024      // timesteps
#define BB   64        // batch
#define FF   256       // input features
#define HH   2048      // LSTM units
#define G4   8192      // 4*H
#define KTOT 2304      // F + H
#define KP   2312      // padded LDS K-stride (elements)
#define NBLK 256
#define NTHR 256
#define ZSTR 34        // z tile LDS row stride (floats), even for float2 alignment
#define SMEM_BYTES (32 * KP * 2 + BB * ZSTR * 4)   // 147968 + 8704 = 156672 B

typedef __attribute__((ext_vector_type(8))) short bf16x8;
typedef __attribute__((ext_vector_type(4))) float f32x4;

__device__ __forceinline__ unsigned short f2bf(float f) {
  unsigned u = __float_as_uint(f);
  u += 0x7FFFu + ((u >> 16) & 1u);        // RNE
  return (unsigned short)(u >> 16);
}
__device__ __forceinline__ float sigm(float x) { return 1.0f / (1.0f + __expf(-x)); }
__device__ __forceinline__ float tanhfast(float x) {
  x = fminf(fmaxf(x, -15.0f), 15.0f);
  float e = __expf(2.0f * x);
  return (e - 1.0f) / (e + 1.0f);
}

// Persistent LSTM: 256 blocks (1/CU), block j owns h-columns [8j,8j+8).
// Per-step sync: write-through h stores (sc0 sc1) + flag-array barrier with
// rotating master + single buffer_inv acquire per block. No wbl2, no atomic RMW.
__global__ void __launch_bounds__(NTHR, 1) lstm_persist(
    const float* __restrict__ x,          // [B][T][F] fp32
    const float* __restrict__ Wk,         // [F][4H]
    const float* __restrict__ Wr,         // [H][4H]
    const float* __restrict__ bias,       // [4H]
    unsigned short* __restrict__ hbuf0,   // [B][H] bf16
    unsigned short* __restrict__ hbuf1,   // [B][H] bf16
    float* __restrict__ hTf,              // [B][H] fp32 (final h)
    unsigned* __restrict__ bar)           // barrier: flags[256] @128B stride, then go
{
  extern __shared__ char smem[];
  unsigned short* Wl = (unsigned short*)smem;        // [32][KP] bf16, column-major
  float* zl = (float*)(smem + 32 * KP * 2);          // [64][ZSTR]

  unsigned* flags = bar;                  // flags[b] at bar[b*32] (128B apart)
  unsigned* go    = bar + NBLK * 32;      // single release word

  const int tid = threadIdx.x;
  const int j = blockIdx.x;

  // ---- stage weight slice into LDS as bf16 (one-time) ----
  for (int idx = tid; idx < 32 * KTOT; idx += NTHR) {
    int cc = idx & 31;
    int k  = idx >> 5;
    int zc = (cc >> 3) * HH + j * 8 + (cc & 7);
    float wv = (k < FF) ? Wk[(size_t)k * G4 + zc] : Wr[(size_t)(k - FF) * G4 + zc];
    Wl[cc * KP + k] = f2bf(wv);
  }
  __syncthreads();

  // MFMA geometry
  const int lane = tid & 63;
  const int wid  = tid >> 6;               // 0..3
  const int row  = wid * 16 + (lane & 15); // batch row for A fragment
  const int ko   = (lane >> 4) * 8;        // k offset within K-step of 32
  const int cl   = lane & 15;              // C/D column within tile
  const int rg   = lane >> 4;              // C/D row group

  // gate mapping: thread -> (batch row bb, column pair col0..col0+1)
  const int hc2  = (tid & 3) * 2;          // 0,2,4,6
  const int bb   = tid >> 2;               // 0..63
  const int col0 = j * 8 + hc2;
  const float bi0 = bias[col0],          bi1 = bias[col0 + 1];
  const float bf0 = bias[HH + col0],     bf1 = bias[HH + col0 + 1];
  const float bg0 = bias[2*HH + col0],   bg1 = bias[2*HH + col0 + 1];
  const float bo0 = bias[3*HH + col0],   bo1 = bias[3*HH + col0 + 1];
  float cA = 0.0f, cB = 0.0f;

  const unsigned short* Wl_b0 = Wl + (0  + cl) * KP;
  const unsigned short* Wl_b1 = Wl + (16 + cl) * KP;
  const unsigned short* Wl_h0 = Wl_b0 + FF;
  const unsigned short* Wl_h1 = Wl_b1 + FF;

  f32x4 acc0, acc1;

  // x-part of z for timestep TSTEP (no dependence on h) -> fresh acc
#define XPART(TSTEP) do {                                                     \
    const float* xr = x + ((size_t)row * TT + (TSTEP)) * FF;                  \
    acc0 = (f32x4){0.f,0.f,0.f,0.f};                                          \
    acc1 = (f32x4){0.f,0.f,0.f,0.f};                                          \
    _Pragma("unroll")                                                         \
    for (int kk = 0; kk < FF; kk += 32) {                                     \
      const float4 v0 = *(const float4*)(xr + kk + ko);                       \
      const float4 v1 = *(const float4*)(xr + kk + ko + 4);                   \
      bf16x8 a;                                                               \
      a[0] = (short)f2bf(v0.x); a[1] = (short)f2bf(v0.y);                     \
      a[2] = (short)f2bf(v0.z); a[3] = (short)f2bf(v0.w);                     \
      a[4] = (short)f2bf(v1.x); a[5] = (short)f2bf(v1.y);                     \
      a[6] = (short)f2bf(v1.z); a[7] = (short)f2bf(v1.w);                     \
      bf16x8 b0 = *(const bf16x8*)(Wl_b0 + kk + ko);                          \
      bf16x8 b1 = *(const bf16x8*)(Wl_b1 + kk + ko);                          \
      acc0 = __builtin_amdgcn_mfma_f32_16x16x32_bf16(a, b0, acc0, 0, 0, 0);   \
      acc1 = __builtin_amdgcn_mfma_f32_16x16x32_bf16(a, b1, acc1, 0, 0, 0);   \
    }                                                                         \
  } while (0)

  XPART(0);   // prologue: x-part for t=0

  for (int t = 0; t < TT; ++t) {
    // ---- wait for h(t) (go >= t); t=0 passes immediately ----
    if (tid == 0) {
      while (__hip_atomic_load(go, __ATOMIC_RELAXED, __HIP_MEMORY_SCOPE_AGENT) < (unsigned)t)
        __builtin_amdgcn_s_sleep(1);
    }
    __syncthreads();
    if (tid < 64)   // one wave invalidates CU L1 + XCD L2 (acquire)
      __builtin_amdgcn_fence(__ATOMIC_ACQUIRE, "agent");
    __syncthreads();

    // ---- h part: k in [256,2304), cached loads (fresh after inv) ----
    const unsigned short* hr = (t & 1) ? hbuf1 : hbuf0;
    const unsigned short* hrow = hr + row * HH;
    #pragma unroll 16
    for (int kk = 0; kk < HH; kk += 32) {
      bf16x8 a  = *(const bf16x8*)(hrow + kk + ko);
      bf16x8 b0 = *(const bf16x8*)(Wl_h0 + kk + ko);
      bf16x8 b1 = *(const bf16x8*)(Wl_h1 + kk + ko);
      acc0 = __builtin_amdgcn_mfma_f32_16x16x32_bf16(a, b0, acc0, 0, 0, 0);
      acc1 = __builtin_amdgcn_mfma_f32_16x16x32_bf16(a, b1, acc1, 0, 0, 0);
    }

    // ---- scatter z to LDS (C/D layout: col = lane&15, row = (lane>>4)*4 + reg) ----
    #pragma unroll
    for (int r = 0; r < 4; ++r) {
      int b = wid * 16 + rg * 4 + r;
      zl[b * ZSTR + cl]      = acc0[r];
      zl[b * ZSTR + 16 + cl] = acc1[r];
    }
    __syncthreads();

    // ---- gates for (bb, col0..col0+1) ----
    {
      const float* zr = zl + bb * ZSTR + hc2;
      float2 zi = *(const float2*)(zr);
      float2 zf = *(const float2*)(zr + 8);
      float2 zg = *(const float2*)(zr + 16);
      float2 zo = *(const float2*)(zr + 24);
      float iA = sigm(zi.x + bi0), iB = sigm(zi.y + bi1);
      float fA = sigm(zf.x + bf0), fB = sigm(zf.y + bf1);
      float gA = tanhfast(zg.x + bg0), gB = tanhfast(zg.y + bg1);
      float oA = sigm(zo.x + bo0), oB = sigm(zo.y + bo1);
      cA = fA * cA + iA * gA;
      cB = fB * cB + iB * gB;
      float hA = oA * tanhfast(cA);
      float hB = oB * tanhfast(cB);
      if (t < TT - 1) {
        unsigned short* hw = (t & 1) ? hbuf0 : hbuf1;
        unsigned hp = (unsigned)f2bf(hA) | ((unsigned)f2bf(hB) << 16);
        __hip_atomic_store((unsigned*)(hw + bb * HH + col0), hp,
                           __ATOMIC_RELAXED, __HIP_MEMORY_SCOPE_AGENT);  // write-through sc0 sc1
      } else {
        hTf[bb * HH + col0]     = hA;
        hTf[bb * HH + col0 + 1] = hB;
      }
    }

    // ---- arrival + rotating-master release + x-part overlap ----
    if (t + 1 < TT) {
      asm volatile("s_waitcnt vmcnt(0)" ::: "memory");   // h stores at LLC
      __syncthreads();                                   // all waves drained, zl reads done
      if (tid == 0)
        __hip_atomic_store(&flags[j * 32], (unsigned)(t + 1),
                           __ATOMIC_RELAXED, __HIP_MEMORY_SCOPE_AGENT);
      if (j == (t & (NBLK - 1))) {                       // master duty rotates
        while (__hip_atomic_load(&flags[tid * 32], __ATOMIC_RELAXED,
                                 __HIP_MEMORY_SCOPE_AGENT) < (unsigned)(t + 1))
          __builtin_amdgcn_s_sleep(1);
        __syncthreads();
        if (tid == 0)
          __hip_atomic_store(go, (unsigned)(t + 1),
                             __ATOMIC_RELAXED, __HIP_MEMORY_SCOPE_AGENT);
      }
      XPART(t + 1);                                      // overlap barrier latency
    }
  }
#undef XPART
}

// Epilogue: y1 = relu(hT @ Wd + bd)  [64,512]
__global__ void dense1(const float* __restrict__ hT, const float* __restrict__ Wd,
                       const float* __restrict__ bd, float* __restrict__ y1) {
  int o = blockIdx.x * blockDim.x + threadIdx.x;
  int b = o >> 9, n = o & 511;
  float acc = bd[n];
  const float* hrow = hT + b * HH;
  const float* wcol = Wd + n;
  #pragma unroll 8
  for (int k = 0; k < HH; ++k) acc = fmaf(hrow[k], wcol[(size_t)k * 512], acc);
  y1[o] = fmaxf(acc, 0.0f);
}

// y = relu(y1 @ Wo + bo)  [64,1]
__global__ void dense2(const float* __restrict__ y1, const float* __restrict__ Wo,
                       const float* __restrict__ bo, float* __restrict__ out) {
  int b = threadIdx.x;
  float acc = bo[0];
  const float* rowp = y1 + b * 512;
  for (int n = 0; n < 512; ++n) acc = fmaf(rowp[n], Wo[n], acc);
  out[b] = fmaxf(acc, 0.0f);
}

extern "C" void kernel_launch(void* const* d_in, const int* in_sizes, int n_in,
                              void* d_out, int out_size, void* d_ws, size_t ws_size,
                              hipStream_t stream) {
  const float* x    = (const float*)d_in[0];
  const float* Wk   = (const float*)d_in[1];
  const float* Wr   = (const float*)d_in[2];
  const float* bias = (const float*)d_in[3];
  const float* Wd   = (const float*)d_in[4];
  const float* bd   = (const float*)d_in[5];
  const float* Wo   = (const float*)d_in[6];
  const float* bo   = (const float*)d_in[7];
  float* out = (float*)d_out;

  // workspace layout
  char* w = (char*)d_ws;
  unsigned short* hbuf0 = (unsigned short*)(w);                // 262144 B
  unsigned short* hbuf1 = (unsigned short*)(w + 262144);       // 262144 B
  float* hTf            = (float*)(w + 524288);                // 524288 B
  float* y1             = (float*)(w + 1048576);               // 131072 B
  unsigned* bar         = (unsigned*)(w + 1179648);            // flags 32KB + go

  // deterministic per-call init (graph-replay safe)
  hipMemsetAsync(hbuf0, 0, (size_t)BB * HH * 2, stream);
  hipMemsetAsync(bar, 0, NBLK * 128 + 128, stream);

  hipFuncSetAttribute((const void*)lstm_persist,
                      hipFuncAttributeMaxDynamicSharedMemorySize, SMEM_BYTES);

  void* args[] = { (void*)&x, (void*)&Wk, (void*)&Wr, (void*)&bias,
                   (void*)&hbuf0, (void*)&hbuf1, (void*)&hTf, (void*)&bar };
  hipLaunchCooperativeKernel((const void*)lstm_persist, dim3(NBLK), dim3(NTHR),
                             args, SMEM_BYTES, stream);

  dense1<<<dim3(128), dim3(256), 0, stream>>>(hTf, Wd, bd, y1);
  dense2<<<dim3(1), dim3(64), 0, stream>>>(y1, Wo, bo, out);
}

// Round 3
// 15008.578 us; speedup vs baseline: 2.4014x; 1.0865x over previous
//
#include <hip/hip_runtime.h>

// Problem constants
#define TT   1024      // timesteps
#define BB   64        // batch
#define FF   256       // input features
#define HH   2048      // LSTM units
#define G4   8192      // 4*H
#define KTOT 2304      // F + H
#define KP   2312      // padded LDS K-stride (elements)
#define NBLK 256
#define NTHR 256
#define ZSTR 34        // z tile LDS row stride (floats)
#define SMEM_BYTES (32 * KP * 2 + BB * ZSTR * 4)   // 147968 + 8704 = 156672 B
#define HBYTES ((size_t)BB * HH * 2)               // one h buffer: 262144 B

typedef __attribute__((ext_vector_type(8))) short bf16x8;
typedef __attribute__((ext_vector_type(4))) float f32x4;

__device__ __forceinline__ unsigned short f2bf(float f) {
  unsigned u = __float_as_uint(f);
  u += 0x7FFFu + ((u >> 16) & 1u);        // RNE
  return (unsigned short)(u >> 16);
}
__device__ __forceinline__ float sigm(float x) { return 1.0f / (1.0f + __expf(-x)); }
__device__ __forceinline__ float tanhfast(float x) {
  x = fminf(fmaxf(x, -15.0f), 15.0f);
  float e = __expf(2.0f * x);
  return (e - 1.0f) / (e + 1.0f);
}

// Persistent LSTM: 256 blocks (1/CU), block j owns h-columns [8j,8j+8).
// h exchange: write-through stores to a rotation of R buffers; readers use
// CACHED loads (L2 serves the broadcast); one acquire-fence (L1+L2 inv) every
// R steps, all blocks at the same step, covers buffer reuse deterministically.
// Barrier: contiguous flag array, all-to-all poll (1 LLC hop), monotonic.
__global__ void __launch_bounds__(NTHR, 1) lstm_persist(
    const float* __restrict__ x,          // [B][T][F] fp32
    const float* __restrict__ Wk,         // [F][4H]
    const float* __restrict__ Wr,         // [H][4H]
    const float* __restrict__ bias,       // [4H]
    unsigned short* __restrict__ hbufs,   // R x [B][H] bf16 rotation
    float* __restrict__ hTf,              // [B][H] fp32 (final h)
    unsigned* __restrict__ flags,         // u32[256], monotonic step counters
    int rmask)                            // R-1 (R = pow2)
{
  extern __shared__ char smem[];
  unsigned short* Wl = (unsigned short*)smem;        // [32][KP] bf16, col-major
  float* zl = (float*)(smem + 32 * KP * 2);          // [64][ZSTR]

  const int tid = threadIdx.x;
  const int j = blockIdx.x;

  // ---- stage weight slice into LDS as bf16 (one-time) ----
  for (int idx = tid; idx < 32 * KTOT; idx += NTHR) {
    int cc = idx & 31;
    int k  = idx >> 5;
    int zc = (cc >> 3) * HH + j * 8 + (cc & 7);
    float wv = (k < FF) ? Wk[(size_t)k * G4 + zc] : Wr[(size_t)(k - FF) * G4 + zc];
    Wl[cc * KP + k] = f2bf(wv);
  }
  __syncthreads();

  // MFMA geometry
  const int lane = tid & 63;
  const int wid  = tid >> 6;               // 0..3
  const int row  = wid * 16 + (lane & 15); // batch row for A fragment
  const int ko   = (lane >> 4) * 8;        // k offset within K-step of 32
  const int cl   = lane & 15;              // C/D column within tile
  const int rg   = lane >> 4;              // C/D row group

  // gate mapping: thread -> (batch row bb, column pair col0..col0+1)
  const int hc2  = (tid & 3) * 2;
  const int bb   = tid >> 2;               // 0..63
  const int col0 = j * 8 + hc2;
  const float bi0 = bias[col0],          bi1 = bias[col0 + 1];
  const float bf0 = bias[HH + col0],     bf1 = bias[HH + col0 + 1];
  const float bg0 = bias[2*HH + col0],   bg1 = bias[2*HH + col0 + 1];
  const float bo0 = bias[3*HH + col0],   bo1 = bias[3*HH + col0 + 1];
  float cA = 0.0f, cB = 0.0f;

  const unsigned short* Wl_b0 = Wl + (0  + cl) * KP;
  const unsigned short* Wl_b1 = Wl + (16 + cl) * KP;
  const unsigned short* Wl_h0 = Wl_b0 + FF;
  const unsigned short* Wl_h1 = Wl_b1 + FF;

  f32x4 acc0, acc1;

#define XPART(TSTEP) do {                                                     \
    const float* xr = x + ((size_t)row * TT + (TSTEP)) * FF;                  \
    acc0 = (f32x4){0.f,0.f,0.f,0.f};                                          \
    acc1 = (f32x4){0.f,0.f,0.f,0.f};                                          \
    _Pragma("unroll")                                                         \
    for (int kk = 0; kk < FF; kk += 32) {                                     \
      const float4 v0 = *(const float4*)(xr + kk + ko);                       \
      const float4 v1 = *(const float4*)(xr + kk + ko + 4);                   \
      bf16x8 a;                                                               \
      a[0] = (short)f2bf(v0.x); a[1] = (short)f2bf(v0.y);                     \
      a[2] = (short)f2bf(v0.z); a[3] = (short)f2bf(v0.w);                     \
      a[4] = (short)f2bf(v1.x); a[5] = (short)f2bf(v1.y);                     \
      a[6] = (short)f2bf(v1.z); a[7] = (short)f2bf(v1.w);                     \
      bf16x8 b0 = *(const bf16x8*)(Wl_b0 + kk + ko);                          \
      bf16x8 b1 = *(const bf16x8*)(Wl_b1 + kk + ko);                          \
      acc0 = __builtin_amdgcn_mfma_f32_16x16x32_bf16(a, b0, acc0, 0, 0, 0);   \
      acc1 = __builtin_amdgcn_mfma_f32_16x16x32_bf16(a, b1, acc1, 0, 0, 0);   \
    }                                                                         \
  } while (0)

  XPART(0);   // prologue: x-part for t=0 (buffer 0 is zeroed; poll skipped)

  for (int t = 0; t < TT; ++t) {
    // ---- wait for h(t): all-to-all flag poll (sc-bypass, always fresh) ----
    if (t > 0) {
      unsigned* f = &flags[tid];
      while (__hip_atomic_load(f, __ATOMIC_RELAXED, __HIP_MEMORY_SCOPE_AGENT)
             < (unsigned)t)
        __builtin_amdgcn_s_sleep(1);
    }
    __syncthreads();

    // ---- periodic acquire fence: L1+L2 invalidate, once per R steps ----
    // Covers rotation-buffer reuse (window R) and cross-replay staleness (t=0).
    if ((t & rmask) == 0)
      __builtin_amdgcn_fence(__ATOMIC_ACQUIRE, "agent");

    // ---- h part: k in [256,2304), CACHED loads (L2 serves the broadcast) ----
    const unsigned short* hr = hbufs + (size_t)(t & rmask) * (BB * HH);
    const unsigned short* hrow = hr + row * HH;
    #pragma unroll 16
    for (int kk = 0; kk < HH; kk += 32) {
      bf16x8 a  = *(const bf16x8*)(hrow + kk + ko);
      bf16x8 b0 = *(const bf16x8*)(Wl_h0 + kk + ko);
      bf16x8 b1 = *(const bf16x8*)(Wl_h1 + kk + ko);
      acc0 = __builtin_amdgcn_mfma_f32_16x16x32_bf16(a, b0, acc0, 0, 0, 0);
      acc1 = __builtin_amdgcn_mfma_f32_16x16x32_bf16(a, b1, acc1, 0, 0, 0);
    }

    // ---- scatter z to LDS (C/D layout: col = lane&15, row = (lane>>4)*4+reg) ----
    #pragma unroll
    for (int r = 0; r < 4; ++r) {
      int b = wid * 16 + rg * 4 + r;
      zl[b * ZSTR + cl]      = acc0[r];
      zl[b * ZSTR + 16 + cl] = acc1[r];
    }
    __syncthreads();

    // ---- gates for (bb, col0..col0+1) ----
    {
      const float* zr = zl + bb * ZSTR + hc2;
      float2 zi = *(const float2*)(zr);
      float2 zf = *(const float2*)(zr + 8);
      float2 zg = *(const float2*)(zr + 16);
      float2 zo = *(const float2*)(zr + 24);
      float iA = sigm(zi.x + bi0), iB = sigm(zi.y + bi1);
      float fA = sigm(zf.x + bf0), fB = sigm(zf.y + bf1);
      float gA = tanhfast(zg.x + bg0), gB = tanhfast(zg.y + bg1);
      float oA = sigm(zo.x + bo0), oB = sigm(zo.y + bo1);
      cA = fA * cA + iA * gA;
      cB = fB * cB + iB * gB;
      float hA = oA * tanhfast(cA);
      float hB = oB * tanhfast(cB);
      if (t < TT - 1) {
        unsigned short* hw = hbufs + (size_t)((t + 1) & rmask) * (BB * HH);
        unsigned hp = (unsigned)f2bf(hA) | ((unsigned)f2bf(hB) << 16);
        __hip_atomic_store((unsigned*)(hw + bb * HH + col0), hp,
                           __ATOMIC_RELAXED, __HIP_MEMORY_SCOPE_AGENT);  // write-through
      } else {
        hTf[bb * HH + col0]     = hA;
        hTf[bb * HH + col0 + 1] = hB;
      }
    }

    // ---- arrival flag + x-part overlap ----
    if (t + 1 < TT) {
      asm volatile("s_waitcnt vmcnt(0)" ::: "memory");   // h stores acked at LLC
      __syncthreads();                                   // all waves drained; zl free
      if (tid == 0)
        __hip_atomic_store(&flags[j], (unsigned)(t + 1),
                           __ATOMIC_RELAXED, __HIP_MEMORY_SCOPE_AGENT);
      asm volatile("" ::: "memory");                     // don't sink flag past XPART
      XPART(t + 1);                                      // overlap barrier stagger
    }
  }
#undef XPART
}

// Epilogue: y1 = relu(hT @ Wd + bd)  [64,512]
__global__ void dense1(const float* __restrict__ hT, const float* __restrict__ Wd,
                       const float* __restrict__ bd, float* __restrict__ y1) {
  int o = blockIdx.x * blockDim.x + threadIdx.x;
  int b = o >> 9, n = o & 511;
  float acc = bd[n];
  const float* hrow = hT + b * HH;
  const float* wcol = Wd + n;
  #pragma unroll 8
  for (int k = 0; k < HH; ++k) acc = fmaf(hrow[k], wcol[(size_t)k * 512], acc);
  y1[o] = fmaxf(acc, 0.0f);
}

// y = relu(y1 @ Wo + bo)  [64,1]
__global__ void dense2(const float* __restrict__ y1, const float* __restrict__ Wo,
                       const float* __restrict__ bo, float* __restrict__ out) {
  int b = threadIdx.x;
  float acc = bo[0];
  const float* rowp = y1 + b * 512;
  for (int n = 0; n < 512; ++n) acc = fmaf(rowp[n], Wo[n], acc);
  out[b] = fmaxf(acc, 0.0f);
}

extern "C" void kernel_launch(void* const* d_in, const int* in_sizes, int n_in,
                              void* d_out, int out_size, void* d_ws, size_t ws_size,
                              hipStream_t stream) {
  const float* x    = (const float*)d_in[0];
  const float* Wk   = (const float*)d_in[1];
  const float* Wr   = (const float*)d_in[2];
  const float* bias = (const float*)d_in[3];
  const float* Wd   = (const float*)d_in[4];
  const float* bd   = (const float*)d_in[5];
  const float* Wo   = (const float*)d_in[6];
  const float* bo   = (const float*)d_in[7];
  float* out = (float*)d_out;

  // Rotation depth: largest pow2 R in [2,16] fitting ws alongside tail buffers.
  const size_t tail = 524288 /*hTf*/ + 131072 /*y1*/ + 4096 /*flags*/;
  int R = 16;
  while (R > 2 && (size_t)R * HBYTES + tail > ws_size) R >>= 1;

  char* w = (char*)d_ws;
  unsigned short* hbufs = (unsigned short*)w;                     // R*256KB
  float* hTf   = (float*)(w + (size_t)R * HBYTES);                // 512KB
  float* y1    = (float*)(w + (size_t)R * HBYTES + 524288);       // 128KB
  unsigned* flags = (unsigned*)(w + (size_t)R * HBYTES + 655360); // 1KB

  // deterministic per-call init (graph-replay safe, async on stream)
  hipMemsetAsync(hbufs, 0, HBYTES, stream);       // h(0) = 0 in buffer 0
  hipMemsetAsync(flags, 0, NBLK * 4, stream);

  hipFuncSetAttribute((const void*)lstm_persist,
                      hipFuncAttributeMaxDynamicSharedMemorySize, SMEM_BYTES);

  int rmask = R - 1;
  void* args[] = { (void*)&x, (void*)&Wk, (void*)&Wr, (void*)&bias,
                   (void*)&hbufs, (void*)&hTf, (void*)&flags, (void*)&rmask };
  hipLaunchCooperativeKernel((const void*)lstm_persist, dim3(NBLK), dim3(NTHR),
                             args, SMEM_BYTES, stream);

  dense1<<<dim3(128), dim3(256), 0, stream>>>(hTf, Wd, bd, y1);
  dense2<<<dim3(1), dim3(64), 0, stream>>>(y1, Wo, bo, out);
}

// Round 4
// 13619.290 us; speedup vs baseline: 2.6464x; 1.1020x over previous
//
#include <hip/hip_runtime.h>

// Problem constants
#define TT   1024      // timesteps
#define BB   64        // batch
#define FF   256       // input features
#define HH   2048      // LSTM units
#define G4   8192      // 4*H
#define KTOT 2304      // F + H
#define KP   2312      // padded LDS K-stride for staging (elements)
#define NBLK 256
#define NTHR 256
#define RR   4         // h rotation depth (pow2)
#define RMASK (RR - 1)
#define WL_BYTES (32 * KP * 2)            // 147,968 B weight staging (dead after init)
#define SMEM_BYTES WL_BYTES               // zl[4][32][68] f32 (34,816 B) overlays Wl
#define HBYTES ((size_t)BB * HH * 2)      // one h buffer: 262,144 B

typedef __attribute__((ext_vector_type(8))) short bf16x8;
typedef __attribute__((ext_vector_type(4))) float f32x4;

__device__ __forceinline__ unsigned short f2bf(float f) {
  unsigned u = __float_as_uint(f);
  u += 0x7FFFu + ((u >> 16) & 1u);        // RNE
  return (unsigned short)(u >> 16);
}
__device__ __forceinline__ float bf2f(unsigned short b) {
  return __uint_as_float((unsigned)b << 16);
}
__device__ __forceinline__ float sigm(float x) { return 1.0f / (1.0f + __expf(-x)); }
__device__ __forceinline__ float tanhfast(float x) {
  x = fminf(fmaxf(x, -15.0f), 15.0f);
  float e = __expf(2.0f * x);
  return (e - 1.0f) / (e + 1.0f);
}

// Persistent LSTM: 256 blocks (1/CU), block j owns h-columns [8j,8j+8).
// NEW: weights live in REGISTERS (144 VGPR/lane of bf16x8 fragments); K is
// split across the 4 waves (576 each); LDS only holds the 4-way partial-z
// reduction tile. h exchange: write-through stores into an R=4 rotation,
// cached reads, one L2-invalidate fence per R steps. Barrier: flag array,
// wave-0-only poll (u64 pairs), XPART overlap on all waves.
__global__ void __launch_bounds__(NTHR, 1) lstm_persist(
    const float* __restrict__ x,          // [B][T][F] fp32
    const float* __restrict__ Wk,         // [F][4H]
    const float* __restrict__ Wr,         // [H][4H]
    const float* __restrict__ bias,       // [4H]
    unsigned short* __restrict__ hbufs,   // RR x [B][H] bf16 rotation
    unsigned* __restrict__ flags)         // u32[256], monotonic step counters
{
  extern __shared__ char smem[];
  unsigned short* Wl = (unsigned short*)smem;   // staging, dead after init
  float* zl = (float*)smem;                     // [4][32][68] partial z overlay

  const int tid = threadIdx.x;
  const int j = blockIdx.x;
  const int lane = tid & 63;
  const int wid  = tid >> 6;               // 0..3  (K-slice owner)
  const int cl   = lane & 15;              // row-in-Mtile / col-in-Ntile
  const int ko   = (lane >> 4) * 8;        // k offset within 32-step
  const int rg   = lane >> 4;              // C/D row group

  // ---- stage weight slice into LDS (coalesced, one-time) ----
  for (int idx = tid; idx < 32 * KTOT; idx += NTHR) {
    int cc = idx & 31;
    int k  = idx >> 5;
    int zc = (cc >> 3) * HH + j * 8 + (cc & 7);
    float wv = (k < FF) ? Wk[(size_t)k * G4 + zc] : Wr[(size_t)(k - FF) * G4 + zc];
    Wl[cc * KP + k] = f2bf(wv);
  }
  __syncthreads();

  // ---- extract this wave's B fragments into registers (one-time) ----
  // wave wid covers: x k in [wid*64, wid*64+64)  (s = 0..1)
  //                  h k in [wid*512, wid*512+512) (s = 2..17, global k +FF)
  bf16x8 bfr[2][18];
  #pragma unroll
  for (int n = 0; n < 2; ++n) {
    #pragma unroll
    for (int s = 0; s < 18; ++s) {
      int kbase = (s < 2) ? (wid * 64 + s * 32)
                          : (FF + wid * 512 + (s - 2) * 32);
      bfr[n][s] = *(const bf16x8*)(Wl + (n * 16 + cl) * KP + kbase + ko);
    }
  }
  __syncthreads();   // Wl dead; zl overlay live from here

  // gate mapping: thread -> (batch row bb, column pair col0..col0+1)
  const int hc2  = (tid & 3) * 2;
  const int bb   = tid >> 2;               // 0..63
  const int col0 = j * 8 + hc2;
  const float bi0 = bias[col0],          bi1 = bias[col0 + 1];
  const float bf0 = bias[HH + col0],     bf1 = bias[HH + col0 + 1];
  const float bg0 = bias[2*HH + col0],   bg1 = bias[2*HH + col0 + 1];
  const float bo0 = bias[3*HH + col0],   bo1 = bias[3*HH + col0 + 1];
  float cA = 0.0f, cB = 0.0f;

  f32x4 acc[4][2];

  // x-projection for step TS: zero acc, 2 k-steps x 4 M-tiles (per wave slice)
#define XPART(TS) do {                                                        \
    _Pragma("unroll")                                                         \
    for (int m = 0; m < 4; ++m) {                                             \
      acc[m][0] = (f32x4){0.f,0.f,0.f,0.f};                                   \
      acc[m][1] = (f32x4){0.f,0.f,0.f,0.f};                                   \
    }                                                                         \
    _Pragma("unroll")                                                         \
    for (int s = 0; s < 2; ++s) {                                             \
      const int kx = wid * 64 + s * 32 + ko;                                  \
      _Pragma("unroll")                                                       \
      for (int m = 0; m < 4; ++m) {                                           \
        const float* xr = x + ((size_t)(m*16 + cl) * TT + (TS)) * FF + kx;    \
        const float4 v0 = *(const float4*)(xr);                               \
        const float4 v1 = *(const float4*)(xr + 4);                           \
        bf16x8 a;                                                             \
        a[0] = (short)f2bf(v0.x); a[1] = (short)f2bf(v0.y);                   \
        a[2] = (short)f2bf(v0.z); a[3] = (short)f2bf(v0.w);                   \
        a[4] = (short)f2bf(v1.x); a[5] = (short)f2bf(v1.y);                   \
        a[6] = (short)f2bf(v1.z); a[7] = (short)f2bf(v1.w);                   \
        acc[m][0] = __builtin_amdgcn_mfma_f32_16x16x32_bf16(a, bfr[0][s], acc[m][0], 0, 0, 0); \
        acc[m][1] = __builtin_amdgcn_mfma_f32_16x16x32_bf16(a, bfr[1][s], acc[m][1], 0, 0, 0); \
      }                                                                       \
    }                                                                         \
  } while (0)

  XPART(0);
  // initial acquire: kill stale L2/L1 lines from previous graph replay
  if (tid < 64) __builtin_amdgcn_fence(__ATOMIC_ACQUIRE, "agent");
  __syncthreads();

  for (int t = 0; t < TT; ++t) {
    // ---- h part: wave's 512-wide K slice, all 64 batch rows, cached loads ----
    const unsigned short* hb = hbufs + (size_t)(t & RMASK) * (BB * HH);
    #pragma unroll
    for (int s = 2; s < 18; ++s) {
      const int kh = wid * 512 + (s - 2) * 32 + ko;
      #pragma unroll
      for (int m = 0; m < 4; ++m) {
        bf16x8 a = *(const bf16x8*)(hb + (size_t)(m*16 + cl) * HH + kh);
        acc[m][0] = __builtin_amdgcn_mfma_f32_16x16x32_bf16(a, bfr[0][s], acc[m][0], 0, 0, 0);
        acc[m][1] = __builtin_amdgcn_mfma_f32_16x16x32_bf16(a, bfr[1][s], acc[m][1], 0, 0, 0);
      }
    }

    // ---- write partial z to LDS: zl[wid][col][bb], b128 per (m,n) ----
    #pragma unroll
    for (int m = 0; m < 4; ++m)
      #pragma unroll
      for (int n = 0; n < 2; ++n)
        *(f32x4*)(zl + (size_t)(wid * 32 + n * 16 + cl) * 68 + m * 16 + rg * 4) = acc[m][n];
    __syncthreads();

    // ---- gates: sum 4 wave-partials, activate, update c, store h ----
    {
      float zs[8];
      #pragma unroll
      for (int g = 0; g < 4; ++g) {
        float s0 = 0.f, s1 = 0.f;
        #pragma unroll
        for (int w = 0; w < 4; ++w) {
          s0 += zl[(size_t)(w * 32 + g * 8 + hc2)     * 68 + bb];
          s1 += zl[(size_t)(w * 32 + g * 8 + hc2 + 1) * 68 + bb];
        }
        zs[2*g] = s0; zs[2*g+1] = s1;
      }
      float iA = sigm(zs[0] + bi0), iB = sigm(zs[1] + bi1);
      float fA = sigm(zs[2] + bf0), fB = sigm(zs[3] + bf1);
      float gA = tanhfast(zs[4] + bg0), gB = tanhfast(zs[5] + bg1);
      float oA = sigm(zs[6] + bo0), oB = sigm(zs[7] + bo1);
      cA = fA * cA + iA * gA;
      cB = fB * cB + iB * gB;
      float hA = oA * tanhfast(cA);
      float hB = oB * tanhfast(cB);
      // write-through (sc0 sc1) -> LLC; slot (t+1)&3; t=TT-1 lands in slot 0 = h_T
      unsigned short* hw = hbufs + (size_t)((t + 1) & RMASK) * (BB * HH);
      unsigned hp = (unsigned)f2bf(hA) | ((unsigned)f2bf(hB) << 16);
      __hip_atomic_store((unsigned*)(hw + (size_t)bb * HH + col0), hp,
                         __ATOMIC_RELAXED, __HIP_MEMORY_SCOPE_AGENT);
    }

    // ---- barrier tail: flag, XPART overlap, wave-0 poll, periodic fence ----
    if (t + 1 < TT) {
      asm volatile("s_waitcnt vmcnt(0)" ::: "memory");   // h stores acked at LLC
      __syncthreads();                                   // gates done, zl free
      if (tid == 0)
        __hip_atomic_store(&flags[j], (unsigned)(t + 1),
                           __ATOMIC_RELAXED, __HIP_MEMORY_SCOPE_AGENT);
      asm volatile("" ::: "memory");
      XPART(t + 1);                                      // all waves overlap wait
      if (wid == 0) {                                    // wave 0: poll 4 flags/lane
        const unsigned target = (unsigned)(t + 1);
        const unsigned long long* fp =
            (const unsigned long long*)(flags + lane * 4);
        for (;;) {
          unsigned long long v0 = __hip_atomic_load(fp,     __ATOMIC_RELAXED, __HIP_MEMORY_SCOPE_AGENT);
          unsigned long long v1 = __hip_atomic_load(fp + 1, __ATOMIC_RELAXED, __HIP_MEMORY_SCOPE_AGENT);
          bool ok = ((unsigned)v0 >= target) & ((unsigned)(v0 >> 32) >= target) &
                    ((unsigned)v1 >= target) & ((unsigned)(v1 >> 32) >= target);
          if (__all(ok)) break;
          __builtin_amdgcn_s_sleep(1);
        }
      }
      __syncthreads();                                   // release waves 1-3
      if (((t + 1) & RMASK) == 0) {                      // acquire inv, 1 per R steps
        if (tid < 64) __builtin_amdgcn_fence(__ATOMIC_ACQUIRE, "agent");
        __syncthreads();
      }
    }
  }
#undef XPART
}

// Epilogue: y1 = relu(hT @ Wd + bd), hT bf16 in rotation slot 0
__global__ void dense1(const unsigned short* __restrict__ hT,
                       const float* __restrict__ Wd,
                       const float* __restrict__ bd,
                       unsigned short* __restrict__ y1) {
  int o = blockIdx.x * blockDim.x + threadIdx.x;   // 0..32767
  int b = o >> 9, n = o & 511;
  float acc = bd[n];
  const unsigned short* hrow = hT + (size_t)b * HH;
  const float* wcol = Wd + n;
  #pragma unroll 8
  for (int k = 0; k < HH; ++k) acc = fmaf(bf2f(hrow[k]), wcol[(size_t)k * 512], acc);
  y1[o] = f2bf(fmaxf(acc, 0.0f));
}

// y = relu(y1 @ Wo + bo)  [64,1]
__global__ void dense2(const unsigned short* __restrict__ y1,
                       const float* __restrict__ Wo,
                       const float* __restrict__ bo,
                       float* __restrict__ out) {
  int b = threadIdx.x;
  float acc = bo[0];
  const unsigned short* rowp = y1 + (size_t)b * 512;
  for (int n = 0; n < 512; ++n) acc = fmaf(bf2f(rowp[n]), Wo[n], acc);
  out[b] = fmaxf(acc, 0.0f);
}

extern "C" void kernel_launch(void* const* d_in, const int* in_sizes, int n_in,
                              void* d_out, int out_size, void* d_ws, size_t ws_size,
                              hipStream_t stream) {
  const float* x    = (const float*)d_in[0];
  const float* Wk   = (const float*)d_in[1];
  const float* Wr   = (const float*)d_in[2];
  const float* bias = (const float*)d_in[3];
  const float* Wd   = (const float*)d_in[4];
  const float* bd   = (const float*)d_in[5];
  const float* Wo   = (const float*)d_in[6];
  const float* bo   = (const float*)d_in[7];
  float* out = (float*)d_out;

  // workspace layout (1,115,136 B total -- fits the proven >=1.18MB ws)
  char* w = (char*)d_ws;
  unsigned short* hbufs = (unsigned short*)w;                   // RR*256KB = 1MB
  unsigned short* y1    = (unsigned short*)(w + RR * HBYTES);   // 64KB (bf16)
  unsigned* flags       = (unsigned*)(w + RR * HBYTES + 65536); // 1KB

  // deterministic per-call init (graph-replay safe)
  hipMemsetAsync(hbufs, 0, HBYTES, stream);       // h(0) = 0 in slot 0
  hipMemsetAsync(flags, 0, NBLK * 4, stream);

  hipFuncSetAttribute((const void*)lstm_persist,
                      hipFuncAttributeMaxDynamicSharedMemorySize, SMEM_BYTES);

  void* args[] = { (void*)&x, (void*)&Wk, (void*)&Wr, (void*)&bias,
                   (void*)&hbufs, (void*)&flags };
  hipLaunchCooperativeKernel((const void*)lstm_persist, dim3(NBLK), dim3(NTHR),
                             args, SMEM_BYTES, stream);

  dense1<<<dim3(128), dim3(256), 0, stream>>>(hbufs /*slot 0 = h_T*/, Wd, bd, y1);
  dense2<<<dim3(1), dim3(64), 0, stream>>>(y1, Wo, bo, out);
}

// Round 6
// 13416.954 us; speedup vs baseline: 2.6863x; 1.0151x over previous
//
#include <hip/hip_runtime.h>

// Problem constants
#define TT   1024      // timesteps
#define BB   64        // batch
#define FF   256       // input features
#define HH   2048      // LSTM units
#define G4   8192      // 4*H
#define KTOT 2304      // F + H
#define KP   2312      // padded LDS K-stride for staging (elements)
#define NBLK 256
#define NTHR 256
#define RR   4         // h rotation depth (pow2)
#define RMASK (RR - 1)
#define WL_BYTES (32 * KP * 2)            // 147,968 B weight staging (dead after init)
#define SMEM_BYTES WL_BYTES               // zl[4][32][68] f32 (34,816 B) overlays Wl
#define HBYTES ((size_t)BB * HH * 2)      // one h buffer: 262,144 B
#define POLL_CAP (1 << 17)                // bounded spin: wrong-answer beats hang

typedef __attribute__((ext_vector_type(8))) short bf16x8;
typedef __attribute__((ext_vector_type(4))) float f32x4;

__device__ __forceinline__ unsigned short f2bf(float f) {
  unsigned u = __float_as_uint(f);
  u += 0x7FFFu + ((u >> 16) & 1u);        // RNE
  return (unsigned short)(u >> 16);
}
__device__ __forceinline__ float bf2f(unsigned short b) {
  return __uint_as_float((unsigned)b << 16);
}
__device__ __forceinline__ float sigm(float x) { return 1.0f / (1.0f + __expf(-x)); }
__device__ __forceinline__ float tanhfast(float x) {
  x = fminf(fmaxf(x, -15.0f), 15.0f);
  float e = __expf(2.0f * x);
  return (e - 1.0f) / (e + 1.0f);
}

// Persistent LSTM, BARRIER-FREE dataflow version.
// 256 blocks (1/CU), block j produces h-columns [8j,8j+8).
// Weights in registers (bf16x8 fragments), K split across the 4 waves.
// h exchange: write-through sc0sc1 stores into an R=4 rotation; consumers use
// CACHED loads gated by per-producer stamps (u32[256], write-through).
// Wave w gates only on its own 64 producers: one 64-lane stamp gather + __all.
// Skew across blocks is provably <=1 step; rotation depth 4 + a per-block
// acquire fence (L1+L2 inv) every 4 steps covers slot reuse and graph replay.
__global__ void __launch_bounds__(NTHR, 1) lstm_persist(
    const float* __restrict__ x,          // [B][T][F] fp32
    const float* __restrict__ Wk,         // [F][4H]
    const float* __restrict__ Wr,         // [H][4H]
    const float* __restrict__ bias,       // [4H]
    unsigned short* __restrict__ hbufs,   // RR x [B][H] bf16 rotation
    unsigned* __restrict__ stamps)        // u32[256], monotonic step stamps
{
  extern __shared__ char smem[];
  unsigned short* Wl = (unsigned short*)smem;   // staging, dead after init
  float* zl = (float*)smem;                     // [4][32][68] partial-z overlay

  const int tid = threadIdx.x;
  const int j = blockIdx.x;
  const int lane = tid & 63;
  const int wid  = tid >> 6;               // 0..3  (K-slice owner)
  const int cl   = lane & 15;
  const int ko   = (lane >> 4) * 8;
  const int rg   = lane >> 4;

  // ---- stage weight slice into LDS (coalesced, one-time) ----
  for (int idx = tid; idx < 32 * KTOT; idx += NTHR) {
    int cc = idx & 31;
    int k  = idx >> 5;
    int zc = (cc >> 3) * HH + j * 8 + (cc & 7);
    float wv = (k < FF) ? Wk[(size_t)k * G4 + zc] : Wr[(size_t)(k - FF) * G4 + zc];
    Wl[cc * KP + k] = f2bf(wv);
  }
  __syncthreads();

  // ---- extract this wave's B fragments into registers (one-time) ----
  bf16x8 bfr[2][18];
  #pragma unroll
  for (int n = 0; n < 2; ++n) {
    #pragma unroll
    for (int s = 0; s < 18; ++s) {
      int kbase = (s < 2) ? (wid * 64 + s * 32)
                          : (FF + wid * 512 + (s - 2) * 32);
      bfr[n][s] = *(const bf16x8*)(Wl + (n * 16 + cl) * KP + kbase + ko);
    }
  }
  __syncthreads();   // Wl dead; zl overlay live from here

  // gate mapping: thread -> (batch row bb, column pair col0..col0+1)
  const int hc2  = (tid & 3) * 2;
  const int bb   = tid >> 2;               // 0..63
  const int col0 = j * 8 + hc2;
  const float bi0 = bias[col0],          bi1 = bias[col0 + 1];
  const float bf0 = bias[HH + col0],     bf1 = bias[HH + col0 + 1];
  const float bg0 = bias[2*HH + col0],   bg1 = bias[2*HH + col0 + 1];
  const float bo0 = bias[3*HH + col0],   bo1 = bias[3*HH + col0 + 1];
  float cA = 0.0f, cB = 0.0f;

  f32x4 acc[4][2];

#define XPART(TS) do {                                                        \
    _Pragma("unroll")                                                         \
    for (int m = 0; m < 4; ++m) {                                             \
      acc[m][0] = (f32x4){0.f,0.f,0.f,0.f};                                   \
      acc[m][1] = (f32x4){0.f,0.f,0.f,0.f};                                   \
    }                                                                         \
    _Pragma("unroll")                                                         \
    for (int s = 0; s < 2; ++s) {                                             \
      const int kx = wid * 64 + s * 32 + ko;                                  \
      _Pragma("unroll")                                                       \
      for (int m = 0; m < 4; ++m) {                                           \
        const float* xr = x + ((size_t)(m*16 + cl) * TT + (TS)) * FF + kx;    \
        const float4 v0 = *(const float4*)(xr);                               \
        const float4 v1 = *(const float4*)(xr + 4);                           \
        bf16x8 a;                                                             \
        a[0] = (short)f2bf(v0.x); a[1] = (short)f2bf(v0.y);                   \
        a[2] = (short)f2bf(v0.z); a[3] = (short)f2bf(v0.w);                   \
        a[4] = (short)f2bf(v1.x); a[5] = (short)f2bf(v1.y);                   \
        a[6] = (short)f2bf(v1.z); a[7] = (short)f2bf(v1.w);                   \
        acc[m][0] = __builtin_amdgcn_mfma_f32_16x16x32_bf16(a, bfr[0][s], acc[m][0], 0, 0, 0); \
        acc[m][1] = __builtin_amdgcn_mfma_f32_16x16x32_bf16(a, bfr[1][s], acc[m][1], 0, 0, 0); \
      }                                                                       \
    }                                                                         \
  } while (0)

  XPART(0);

  for (int t = 0; t < TT; ++t) {
    // ---- periodic acquire fence (per block): covers rotation-slot reuse and
    //      cross-replay staleness; fires at t=0,4,8,... BEFORE polls/reads ----
    if ((t & RMASK) == 0) {
      if (tid < 64) __builtin_amdgcn_fence(__ATOMIC_ACQUIRE, "agent");
      __syncthreads();
    }

    // ---- per-wave stamp wait: h(t) slice ready from my 64 producers ----
    if (t > 0) {
      const unsigned* sp = stamps + wid * 64 + lane;
      for (int it = 0; it < POLL_CAP; ++it) {
        unsigned v = __hip_atomic_load(sp, __ATOMIC_RELAXED, __HIP_MEMORY_SCOPE_AGENT);
        if (__all((int)(v >= (unsigned)t))) break;
      }
      asm volatile("" ::: "memory");   // no h-load hoists above the poll
    }

    // ---- h part: wave's 512-wide K slice, all 64 batch rows, cached loads ----
    const unsigned short* hb = hbufs + (size_t)(t & RMASK) * (BB * HH);
    #pragma unroll
    for (int s = 2; s < 18; ++s) {
      const int kh = wid * 512 + (s - 2) * 32 + ko;
      #pragma unroll
      for (int m = 0; m < 4; ++m) {
        bf16x8 a = *(const bf16x8*)(hb + (size_t)(m*16 + cl) * HH + kh);
        acc[m][0] = __builtin_amdgcn_mfma_f32_16x16x32_bf16(a, bfr[0][s], acc[m][0], 0, 0, 0);
        acc[m][1] = __builtin_amdgcn_mfma_f32_16x16x32_bf16(a, bfr[1][s], acc[m][1], 0, 0, 0);
      }
    }

    // ---- write partial z to LDS: zl[wid][col][bb] ----
    #pragma unroll
    for (int m = 0; m < 4; ++m)
      #pragma unroll
      for (int n = 0; n < 2; ++n)
        *(f32x4*)(zl + (size_t)(wid * 32 + n * 16 + cl) * 68 + m * 16 + rg * 4) = acc[m][n];
    __syncthreads();

    // ---- gates: sum 4 wave-partials, activate, update c, store h ----
    {
      float zs[8];
      #pragma unroll
      for (int g = 0; g < 4; ++g) {
        float s0 = 0.f, s1 = 0.f;
        #pragma unroll
        for (int w = 0; w < 4; ++w) {
          s0 += zl[(size_t)(w * 32 + g * 8 + hc2)     * 68 + bb];
          s1 += zl[(size_t)(w * 32 + g * 8 + hc2 + 1) * 68 + bb];
        }
        zs[2*g] = s0; zs[2*g+1] = s1;
      }
      float iA = sigm(zs[0] + bi0), iB = sigm(zs[1] + bi1);
      float fA = sigm(zs[2] + bf0), fB = sigm(zs[3] + bf1);
      float gA = tanhfast(zs[4] + bg0), gB = tanhfast(zs[5] + bg1);
      float oA = sigm(zs[6] + bo0), oB = sigm(zs[7] + bo1);
      cA = fA * cA + iA * gA;
      cB = fB * cB + iB * gB;
      float hA = oA * tanhfast(cA);
      float hB = oB * tanhfast(cB);
      // write-through (sc0 sc1); slot (t+1)&3; t=TT-1 lands in slot 0 = h_T
      unsigned short* hw = hbufs + (size_t)((t + 1) & RMASK) * (BB * HH);
      unsigned hp = (unsigned)f2bf(hA) | ((unsigned)f2bf(hB) << 16);
      __hip_atomic_store((unsigned*)(hw + (size_t)bb * HH + col0), hp,
                         __ATOMIC_RELAXED, __HIP_MEMORY_SCOPE_AGENT);
    }

    // ---- publish stamp + XPART overlap (no barrier) ----
    if (t + 1 < TT) {
      asm volatile("s_waitcnt vmcnt(0)" ::: "memory");   // h stores at LLC
      __syncthreads();                                   // whole block drained; zl free
      if (tid == 0)
        __hip_atomic_store(&stamps[j], (unsigned)(t + 1),
                           __ATOMIC_RELAXED, __HIP_MEMORY_SCOPE_AGENT);
      asm volatile("" ::: "memory");                     // keep stamp before XPART
      XPART(t + 1);                                      // overlap consumers' polls
    }
  }
#undef XPART
}

// Fused epilogue: out = relu(relu(hT @ Wd + bd) @ Wo + bo), one block per batch row
__global__ void dense_fused(const unsigned short* __restrict__ hT,
                            const float* __restrict__ Wd,
                            const float* __restrict__ bd,
                            const float* __restrict__ Wo,
                            const float* __restrict__ bo,
                            float* __restrict__ out) {
  __shared__ float hrow[HH];
  __shared__ float y1s[512];
  __shared__ float red[256];
  const int b = blockIdx.x, tid = threadIdx.x;
  for (int k = tid; k < HH; k += 256) hrow[k] = bf2f(hT[(size_t)b * HH + k]);
  __syncthreads();
  for (int c = tid; c < 512; c += 256) {
    float acc = bd[c];
    #pragma unroll 8
    for (int k = 0; k < HH; ++k) acc = fmaf(hrow[k], Wd[(size_t)k * 512 + c], acc);
    y1s[c] = fmaxf(acc, 0.0f);
  }
  __syncthreads();
  red[tid] = y1s[tid] * Wo[tid] + y1s[tid + 256] * Wo[tid + 256];
  __syncthreads();
  for (int st = 128; st > 0; st >>= 1) {
    if (tid < st) red[tid] += red[tid + st];
    __syncthreads();
  }
  if (tid == 0) out[b] = fmaxf(red[0] + bo[0], 0.0f);
}

extern "C" void kernel_launch(void* const* d_in, const int* in_sizes, int n_in,
                              void* d_out, int out_size, void* d_ws, size_t ws_size,
                              hipStream_t stream) {
  const float* x    = (const float*)d_in[0];
  const float* Wk   = (const float*)d_in[1];
  const float* Wr   = (const float*)d_in[2];
  const float* bias = (const float*)d_in[3];
  const float* Wd   = (const float*)d_in[4];
  const float* bd   = (const float*)d_in[5];
  const float* Wo   = (const float*)d_in[6];
  const float* bo   = (const float*)d_in[7];
  float* out = (float*)d_out;

  // workspace layout: hbufs 1 MB + stamps 1 KB
  char* w = (char*)d_ws;
  unsigned short* hbufs = (unsigned short*)w;                   // RR*256KB = 1MB
  unsigned* stamps      = (unsigned*)(w + RR * HBYTES);         // 1 KB

  // deterministic per-call init (graph-replay safe)
  hipMemsetAsync(hbufs, 0, HBYTES, stream);       // h(0) = 0 in slot 0
  hipMemsetAsync(stamps, 0, NBLK * 4, stream);

  hipFuncSetAttribute((const void*)lstm_persist,
                      hipFuncAttributeMaxDynamicSharedMemorySize, SMEM_BYTES);

  void* args[] = { (void*)&x, (void*)&Wk, (void*)&Wr, (void*)&bias,
                   (void*)&hbufs, (void*)&stamps };
  hipLaunchCooperativeKernel((const void*)lstm_persist, dim3(NBLK), dim3(NTHR),
                             args, SMEM_BYTES, stream);

  dense_fused<<<dim3(BB), dim3(256), 0, stream>>>(hbufs /*slot 0 = h_T*/,
                                                  Wd, bd, Wo, bo, out);
}